// Round 4
// baseline (907.524 us; speedup 1.0000x reference)
//
#include <hip/hip_runtime.h>
#include <hip/hip_bf16.h>
#include <math.h>

typedef __bf16 bf16_t;
typedef __bf16 bf16x8 __attribute__((ext_vector_type(8)));
typedef __bf16 bf16x4v __attribute__((ext_vector_type(4)));
typedef float f32x4 __attribute__((ext_vector_type(4)));

#define SCALE_F 0.08838834764831845f  // 1/sqrt(128)
#define SMAX_F 14.0f                  // fixed softmax max (score <= sqrt(128)=11.32, g=1)
#define OBLD 3712                     // packed x-GEMM output row stride (3648 padded)

// async global->LDS, 16B per lane; LDS dest = wave-uniform base + lane*16
#define GLOAD_LDS16(gp, lp)                                              \
    __builtin_amdgcn_global_load_lds(                                    \
        (const __attribute__((address_space(1))) void*)(gp),             \
        (__attribute__((address_space(3))) void*)(lp), 16, 0, 0)

// ---------------- fp32 -> bf16 convert ----------------
__global__ void k_convert(const float* __restrict__ in, bf16_t* __restrict__ out, int n) {
    int i = (blockIdx.x * 256 + threadIdx.x) * 4;
    if (i >= n) return;
    float4 f = *(const float4*)(in + i);
    out[i + 0] = (bf16_t)f.x;
    out[i + 1] = (bf16_t)f.y;
    out[i + 2] = (bf16_t)f.z;
    out[i + 3] = (bf16_t)f.w;
}

// ---------------- transpose + convert: w[K][N] -> wt[N][K] bf16 ----------------
__global__ void k_transpose(const float* __restrict__ w, bf16_t* __restrict__ wt, int K, int N) {
    __shared__ float tile[32][33];
    int n0 = blockIdx.x * 32, k0 = blockIdx.y * 32;
    int tx = threadIdx.x & 31, ty = threadIdx.x >> 5;  // 32x8
#pragma unroll
    for (int i = 0; i < 32; i += 8)
        tile[ty + i][tx] = w[(size_t)(k0 + ty + i) * N + (n0 + tx)];
    __syncthreads();
#pragma unroll
    for (int i = 0; i < 32; i += 8)
        wt[(size_t)(n0 + ty + i) * K + (k0 + tx)] = (bf16_t)tile[tx][ty + i];
}

// ---------------- rope tables: cs[t*64+i] = (cos, sin) ----------------
__global__ void k_rope_tables(float2* __restrict__ cs) {
    int idx = blockIdx.x * 256 + threadIdx.x;  // t*64 + i
    int t = idx >> 6, i = idx & 63;
    float invf = powf(10000.f, -(float)(i & 31) / 32.f);
    float ang = (float)t * invf;
    float s, c;
    sincosf(ang, &s, &c);
    cs[idx] = make_float2(c, s);
}

// ---------------- fused rmsnorm of packed cols [0,1024) and [1024,1536) ----------------
__global__ void k_rmsnorm2(bf16_t* __restrict__ ob, const float* __restrict__ g1,
                           const float* __restrict__ g2) {
    bf16_t* p = ob + (size_t)blockIdx.x * OBLD;
    const int tid = threadIdx.x;
    __shared__ float red[4];
    // part 1: qc cols [0,1024)
    bf16x4v v = *(bf16x4v*)(p + tid * 4);
    float a0 = (float)v[0], a1 = (float)v[1], a2 = (float)v[2], a3 = (float)v[3];
    float ss = a0 * a0 + a1 * a1 + a2 * a2 + a3 * a3;
#pragma unroll
    for (int m = 32; m; m >>= 1) ss += __shfl_xor(ss, m);
    if ((tid & 63) == 0) red[tid >> 6] = ss;
    __syncthreads();
    float sc1 = rsqrtf((red[0] + red[1] + red[2] + red[3]) / 1024.f + 1e-6f);
    v[0] = (bf16_t)(a0 * sc1 * g1[tid * 4 + 0]);
    v[1] = (bf16_t)(a1 * sc1 * g1[tid * 4 + 1]);
    v[2] = (bf16_t)(a2 * sc1 * g1[tid * 4 + 2]);
    v[3] = (bf16_t)(a3 * sc1 * g1[tid * 4 + 3]);
    *(bf16x4v*)(p + tid * 4) = v;
    // part 2: ckv cols [1024,1536)
    float b0 = (float)p[1024 + tid * 2], b1 = (float)p[1024 + tid * 2 + 1];
    float ss2 = b0 * b0 + b1 * b1;
#pragma unroll
    for (int m = 32; m; m >>= 1) ss2 += __shfl_xor(ss2, m);
    __syncthreads();  // everyone done reading red
    if ((tid & 63) == 0) red[tid >> 6] = ss2;
    __syncthreads();
    float sc2 = rsqrtf((red[0] + red[1] + red[2] + red[3]) / 512.f + 1e-6f);
    p[1024 + tid * 2] = (bf16_t)(b0 * sc2 * g2[tid * 2]);
    p[1024 + tid * 2 + 1] = (bf16_t)(b1 * sc2 * g2[tid * 2 + 1]);
}

// ---------------- GEMM (m97 structure): C[M][N] = A[M][K] @ Bt[N][K]^T ----------------
// 128x128 tile, BK=32, LDS staged via global_load_lds w=16. Strided + batched.
template <int OUTF32>
__global__ __launch_bounds__(256) void k_gemm(const bf16_t* __restrict__ A, int lda,
                                              const bf16_t* __restrict__ Bt, int ldb,
                                              void* __restrict__ Cp, int ldc, int M, int N, int K,
                                              size_t sA, size_t sB, size_t sC) {
    __shared__ bf16_t As[128 * 32];
    __shared__ bf16_t Bs[128 * 32];
    A += (size_t)blockIdx.z * sA;
    Bt += (size_t)blockIdx.z * sB;
    const size_t coff = (size_t)blockIdx.z * sC;
    const int bm = blockIdx.y * 128, bn = blockIdx.x * 128;
    const int tid = threadIdx.x, lane = tid & 63, wv = tid >> 6;
    const int quad = lane >> 4, l16 = lane & 15;
    const int wm = (wv >> 1) * 64, wn = (wv & 1) * 64;
    f32x4 acc[4][4] = {};
    const int sr0 = wv * 32 + (lane >> 2);
    const int scc = (lane & 3) * 8;
    bf16_t* ldsA0 = As + (wv * 2) * 512;
    bf16_t* ldsA1 = As + (wv * 2 + 1) * 512;
    bf16_t* ldsB0 = Bs + (wv * 2) * 512;
    bf16_t* ldsB1 = Bs + (wv * 2 + 1) * 512;
    const bool bok0 = (bn + sr0) < N;
    const bool bok1 = (bn + sr0 + 16) < N;
    for (int k0 = 0; k0 < K; k0 += 32) {
        const bf16_t* gA = A + (size_t)(bm + sr0) * lda + k0 + scc;
        const bf16_t* gB = Bt + (size_t)(bn + sr0) * ldb + k0 + scc;
        GLOAD_LDS16(gA, ldsA0);
        GLOAD_LDS16(gA + (size_t)16 * lda, ldsA1);
        if (bok0) GLOAD_LDS16(gB, ldsB0);
        if (bok1) GLOAD_LDS16(gB + (size_t)16 * ldb, ldsB1);
        __syncthreads();
        bf16x8 af[4], bfr[4];
#pragma unroll
        for (int mi = 0; mi < 4; ++mi)
            af[mi] = *(bf16x8*)(As + (wm + mi * 16 + l16) * 32 + quad * 8);
#pragma unroll
        for (int ni = 0; ni < 4; ++ni)
            bfr[ni] = *(bf16x8*)(Bs + (wn + ni * 16 + l16) * 32 + quad * 8);
#pragma unroll
        for (int mi = 0; mi < 4; ++mi)
#pragma unroll
            for (int ni = 0; ni < 4; ++ni)
                acc[mi][ni] =
                    __builtin_amdgcn_mfma_f32_16x16x32_bf16(af[mi], bfr[ni], acc[mi][ni], 0, 0, 0);
        __syncthreads();
    }
#pragma unroll
    for (int mi = 0; mi < 4; ++mi)
#pragma unroll
        for (int ni = 0; ni < 4; ++ni)
#pragma unroll
            for (int r = 0; r < 4; ++r) {
                int row = bm + wm + mi * 16 + quad * 4 + r;
                int col = bn + wn + ni * 16 + l16;
                if (col < N) {
                    if constexpr (OUTF32)
                        ((float*)Cp)[coff + (size_t)row * ldc + col] = acc[mi][ni][r];
                    else
                        ((bf16_t*)Cp)[coff + (size_t)row * ldc + col] = (bf16_t)acc[mi][ni][r];
                }
            }
}

// ---------------- q_up GEMM with fused rope + per-head rmsnorm epilogue ----------------
// N=2048 = 16 heads * 128; N-block == head. wn=0 waves: nope cols; wn=64: rope cols.
__global__ __launch_bounds__(256) void k_gemm_qup(const bf16_t* __restrict__ A, int lda,
                                                  const bf16_t* __restrict__ Bt,
                                                  bf16_t* __restrict__ Cq,
                                                  const float* __restrict__ g_q,
                                                  const float2* __restrict__ cs, int K) {
    __shared__ bf16_t As[128 * 32];
    __shared__ bf16_t Bs[128 * 32];
    __shared__ float red[2][128];
    const int ldb = K;
    const int bm = blockIdx.y * 128, bn = blockIdx.x * 128;
    const int h = blockIdx.x;
    const int tid = threadIdx.x, lane = tid & 63, wv = tid >> 6;
    const int quad = lane >> 4, l16 = lane & 15;
    const int wm = (wv >> 1) * 64, wn = (wv & 1) * 64;
    f32x4 acc[4][4] = {};
    const int sr0 = wv * 32 + (lane >> 2);
    const int scc = (lane & 3) * 8;
    bf16_t* ldsA0 = As + (wv * 2) * 512;
    bf16_t* ldsA1 = As + (wv * 2 + 1) * 512;
    bf16_t* ldsB0 = Bs + (wv * 2) * 512;
    bf16_t* ldsB1 = Bs + (wv * 2 + 1) * 512;
    for (int k0 = 0; k0 < K; k0 += 32) {
        const bf16_t* gA = A + (size_t)(bm + sr0) * lda + k0 + scc;
        const bf16_t* gB = Bt + (size_t)(bn + sr0) * ldb + k0 + scc;
        GLOAD_LDS16(gA, ldsA0);
        GLOAD_LDS16(gA + (size_t)16 * lda, ldsA1);
        GLOAD_LDS16(gB, ldsB0);
        GLOAD_LDS16(gB + (size_t)16 * ldb, ldsB1);
        __syncthreads();
        bf16x8 af[4], bfr[4];
#pragma unroll
        for (int mi = 0; mi < 4; ++mi)
            af[mi] = *(bf16x8*)(As + (wm + mi * 16 + l16) * 32 + quad * 8);
#pragma unroll
        for (int ni = 0; ni < 4; ++ni)
            bfr[ni] = *(bf16x8*)(Bs + (wn + ni * 16 + l16) * 32 + quad * 8);
#pragma unroll
        for (int mi = 0; mi < 4; ++mi)
#pragma unroll
            for (int ni = 0; ni < 4; ++ni)
                acc[mi][ni] =
                    __builtin_amdgcn_mfma_f32_16x16x32_bf16(af[mi], bfr[ni], acc[mi][ni], 0, 0, 0);
        __syncthreads();
    }
    // --- rope on the upper-half waves (cols 64..127 of the head) ---
    if (wn) {
#pragma unroll
        for (int mi = 0; mi < 4; ++mi)
#pragma unroll
            for (int r = 0; r < 4; ++r) {
                int t = (bm + wm + mi * 16 + quad * 4 + r) & 2047;
                float2 c0 = cs[t * 64 + 0 * 16 + l16];
                float2 c1 = cs[t * 64 + 1 * 16 + l16];
                float2 c2 = cs[t * 64 + 2 * 16 + l16];
                float2 c3 = cs[t * 64 + 3 * 16 + l16];
                float a0 = acc[mi][0][r], a1 = acc[mi][1][r];
                float a2 = acc[mi][2][r], a3 = acc[mi][3][r];
                acc[mi][0][r] = a0 * c0.x - a2 * c0.y;
                acc[mi][1][r] = a1 * c1.x - a3 * c1.y;
                acc[mi][2][r] = a2 * c2.x + a0 * c2.y;
                acc[mi][3][r] = a3 * c3.x + a1 * c3.y;
            }
    }
    // --- per-row sum of squares (64 cols in this wave), cross-wave via LDS ---
#pragma unroll
    for (int mi = 0; mi < 4; ++mi)
#pragma unroll
        for (int r = 0; r < 4; ++r) {
            float ss = acc[mi][0][r] * acc[mi][0][r] + acc[mi][1][r] * acc[mi][1][r] +
                       acc[mi][2][r] * acc[mi][2][r] + acc[mi][3][r] * acc[mi][3][r];
#pragma unroll
            for (int m = 8; m; m >>= 1) ss += __shfl_xor(ss, m);
            if (l16 == 0) red[wn >> 6][wm + mi * 16 + quad * 4 + r] = ss;
        }
    __syncthreads();
    // --- normalize, apply g_q, store ---
    float gv[4];
#pragma unroll
    for (int ni = 0; ni < 4; ++ni) gv[ni] = g_q[wn + ni * 16 + l16];
#pragma unroll
    for (int mi = 0; mi < 4; ++mi)
#pragma unroll
        for (int r = 0; r < 4; ++r) {
            int row = wm + mi * 16 + quad * 4 + r;
            float tot = red[0][row] + red[1][row];
            float scale = rsqrtf(tot / 128.f + 1e-6f);
            size_t gi = (size_t)(bm + row) * 2048 + h * 128 + wn + l16;
#pragma unroll
            for (int ni = 0; ni < 4; ++ni)
                Cq[gi + ni * 16] = (bf16_t)(acc[mi][ni][r] * scale * gv[ni]);
        }
}

// ---------------- build k: gather nope + roped shared rope, rmsnorm ----------------
__global__ void k_build_k(const bf16_t* __restrict__ knope, const bf16_t* __restrict__ krope,
                          bf16_t* __restrict__ kout, const float* __restrict__ g,
                          const float2* __restrict__ cs) {
    int wid = blockIdx.x * 4 + (threadIdx.x >> 6);
    int lane = threadIdx.x & 63;
    int row = wid >> 4, h = wid & 15;
    int t = row & 2047;
    float x0 = (float)knope[(size_t)row * 1024 + h * 64 + lane];
    float x1 = (float)krope[(size_t)row * OBLD + lane];
    float xp = (float)krope[(size_t)row * OBLD + (lane ^ 32)];
    float2 c = cs[t * 64 + lane];
    float rot = (lane < 32) ? -xp : xp;
    float y1 = x1 * c.x + rot * c.y;
    float ss = x0 * x0 + y1 * y1;
#pragma unroll
    for (int m = 32; m; m >>= 1) ss += __shfl_xor(ss, m);
    float scale = rsqrtf(ss / 128.f + 1e-6f);
    bf16_t* p = kout + (size_t)row * 2048 + h * 128;
    p[lane] = (bf16_t)(x0 * scale * g[lane]);
    p[64 + lane] = (bf16_t)(y1 * scale * g[64 + lane]);
}

// ---------------- flash attention + silu(gate), fixed-max softmax ----------------
// grid (T/128, B*H), 256 thr = 4 waves; wave w owns 32 q-rows (2x16 strips).
__global__ __launch_bounds__(256) void k_attn(const bf16_t* __restrict__ q,
                                              const bf16_t* __restrict__ k,
                                              const bf16_t* __restrict__ vT,
                                              const bf16_t* __restrict__ gate,
                                              bf16_t* __restrict__ o) {
    __shared__ bf16_t Ks[64 * 136];  // [s][128 d +8]
    __shared__ bf16_t Vt[128 * 72];  // [d][64 s +8]
    __shared__ bf16_t Ps[128 * 72];  // [t][64 s +8]
    const int qb = (int)gridDim.x - 1 - (int)blockIdx.x;  // long blocks first
    const int bh = blockIdx.y;
    const int b = bh >> 4, h = bh & 15;
    const int t0 = qb * 128;
    const int tid = threadIdx.x, lane = tid & 63, wv = tid >> 6;  // wv 0..3
    const int quad = lane >> 4, l16 = lane & 15;
    const int wrow = t0 + wv * 32;

    bf16x8 aq[2][4];
#pragma unroll
    for (int s = 0; s < 2; ++s) {
        const bf16_t* qp =
            q + ((size_t)(b * 2048 + wrow + s * 16 + l16)) * 2048 + h * 128 + quad * 8;
#pragma unroll
        for (int kk = 0; kk < 4; ++kk) aq[s][kk] = *(const bf16x8*)(qp + kk * 32);
    }
    f32x4 oacc[2][8] = {};
    float l_i[2][4] = {};

    const bf16_t* kbase = k + ((size_t)b * 2048) * 2048 + h * 128;
    const bf16_t* vbase = vT + ((size_t)b * 2048 + (size_t)h * 128) * 2048;

    const int krow = tid >> 4, kcol = (tid & 15) * 8;  // K: 16 rows x4
    const int vrow = tid >> 3, vcol = (tid & 7) * 8;   // Vt: 32 rows x4

    const int nkb = 2 * qb + 2;
    bf16x8 kreg[4], vreg[4];
#pragma unroll
    for (int p = 0; p < 4; ++p) {
        kreg[p] = *(const bf16x8*)(kbase + (size_t)(krow + p * 16) * 2048 + kcol);
        vreg[p] = *(const bf16x8*)(vbase + (size_t)(vrow + p * 32) * 2048 + vcol);
    }
    for (int kb = 0; kb < nkb; ++kb) {
        const int s0 = kb * 64;
        __syncthreads();
#pragma unroll
        for (int p = 0; p < 4; ++p) {
            *(bf16x8*)(Ks + (krow + p * 16) * 136 + kcol) = kreg[p];
            *(bf16x8*)(Vt + (vrow + p * 32) * 72 + vcol) = vreg[p];
        }
        __syncthreads();
        if (kb + 1 < nkb) {
            const int sn = s0 + 64;
#pragma unroll
            for (int p = 0; p < 4; ++p) {
                kreg[p] = *(const bf16x8*)(kbase + (size_t)(sn + krow + p * 16) * 2048 + kcol);
                vreg[p] = *(const bf16x8*)(vbase + (size_t)(vrow + p * 32) * 2048 + sn + vcol);
            }
        }
        if (s0 > wrow + 31) continue;  // wave fully above diagonal
        // S = Q K^T for both strips; bk shared
        f32x4 sc[2][4] = {};
#pragma unroll
        for (int kk = 0; kk < 4; ++kk)
#pragma unroll
            for (int ni = 0; ni < 4; ++ni) {
                bf16x8 bk = *(bf16x8*)(Ks + (ni * 16 + l16) * 136 + kk * 32 + quad * 8);
                sc[0][ni] = __builtin_amdgcn_mfma_f32_16x16x32_bf16(aq[0][kk], bk, sc[0][ni], 0, 0, 0);
                sc[1][ni] = __builtin_amdgcn_mfma_f32_16x16x32_bf16(aq[1][kk], bk, sc[1][ni], 0, 0, 0);
            }
        // fixed-max softmax + mask per strip
#pragma unroll
        for (int s = 0; s < 2; ++s) {
            const int trowb = wrow + s * 16 + quad * 4;
            const bool diag = (s0 + 63 > trowb + 3) | true;  // cheap: always mask-check
#pragma unroll
            for (int ni = 0; ni < 4; ++ni) {
                int scol = s0 + ni * 16 + l16;
#pragma unroll
                for (int r2 = 0; r2 < 4; ++r2) {
                    float pv = __expf(sc[s][ni][r2] * SCALE_F - SMAX_F);
                    if (scol > trowb + r2) pv = 0.f;
                    sc[s][ni][r2] = pv;
                    l_i[s][r2] += pv;
                }
            }
            (void)diag;
#pragma unroll
            for (int ni = 0; ni < 4; ++ni)
#pragma unroll
                for (int r2 = 0; r2 < 4; ++r2)
                    Ps[(wv * 32 + s * 16 + quad * 4 + r2) * 72 + ni * 16 + l16] =
                        (bf16_t)sc[s][ni][r2];
        }
        // O += P V ; bv shared between strips
#pragma unroll
        for (int kk = 0; kk < 2; ++kk) {
            bf16x8 ap0 = *(bf16x8*)(Ps + (wv * 32 + l16) * 72 + kk * 32 + quad * 8);
            bf16x8 ap1 = *(bf16x8*)(Ps + (wv * 32 + 16 + l16) * 72 + kk * 32 + quad * 8);
#pragma unroll
            for (int ni = 0; ni < 8; ++ni) {
                bf16x8 bv = *(bf16x8*)(Vt + (ni * 16 + l16) * 72 + kk * 32 + quad * 8);
                oacc[0][ni] = __builtin_amdgcn_mfma_f32_16x16x32_bf16(ap0, bv, oacc[0][ni], 0, 0, 0);
                oacc[1][ni] = __builtin_amdgcn_mfma_f32_16x16x32_bf16(ap1, bv, oacc[1][ni], 0, 0, 0);
            }
        }
    }
#pragma unroll
    for (int s = 0; s < 2; ++s) {
#pragma unroll
        for (int m = 8; m; m >>= 1)
#pragma unroll
            for (int r2 = 0; r2 < 4; ++r2) l_i[s][r2] += __shfl_xor(l_i[s][r2], m);
        float rl[4];
#pragma unroll
        for (int r2 = 0; r2 < 4; ++r2) rl[r2] = 1.f / l_i[s][r2];
#pragma unroll
        for (int ni = 0; ni < 8; ++ni) {
            int d = ni * 16 + l16;
#pragma unroll
            for (int r2 = 0; r2 < 4; ++r2) {
                int trow = wrow + s * 16 + quad * 4 + r2;
                size_t grow = (size_t)(b * 2048 + trow);
                float gt = (float)gate[grow * OBLD + 1600 + h * 128 + d];
                float sg = gt / (1.f + __expf(-gt));
                o[grow * 2048 + h * 128 + d] = (bf16_t)((oacc[s][ni][r2] * rl[r2]) * sg);
            }
        }
    }
}

extern "C" void kernel_launch(void* const* d_in, const int* in_sizes, int n_in,
                              void* d_out, int out_size, void* d_ws, size_t ws_size,
                              hipStream_t stream) {
    const float* x         = (const float*)d_in[0];
    const float* w_q_down  = (const float*)d_in[1];
    const float* g_q_down  = (const float*)d_in[2];
    const float* w_q_up    = (const float*)d_in[3];
    const float* w_kv_down = (const float*)d_in[4];
    const float* g_kv_down = (const float*)d_in[5];
    const float* w_k_up    = (const float*)d_in[6];
    const float* w_v_up    = (const float*)d_in[7];
    const float* w_k_rope  = (const float*)d_in[8];
    const float* g_q       = (const float*)d_in[9];
    const float* g_k       = (const float*)d_in[10];
    const float* w_gate    = (const float*)d_in[11];
    const float* w_o       = (const float*)d_in[12];
    float* out = (float*)d_out;

    char* base = (char*)d_ws;
    size_t off = 0;
    auto alloc = [&](size_t bytes) -> void* {
        void* p = base + off;
        off = (off + bytes + 255) & ~(size_t)255;
        return p;
    };
    const size_t MT = 8192;  // B*T
    bf16_t* xb    = (bf16_t*)alloc(MT * 2048 * 2);
    bf16_t* Wt    = (bf16_t*)alloc((size_t)OBLD * 2048 * 2);  // packed: qd|kvd|kr|gate
    bf16_t* wqu_t = (bf16_t*)alloc((size_t)2048 * 1024 * 2);
    bf16_t* wku_t = (bf16_t*)alloc((size_t)1024 * 512 * 2);
    bf16_t* wvu_t = (bf16_t*)alloc((size_t)2048 * 512 * 2);
    bf16_t* wo_t  = (bf16_t*)alloc((size_t)2048 * 2048 * 2);
    bf16_t* ob    = (bf16_t*)alloc(MT * OBLD * 2);  // [qc|ckv|krope|gate] per row
    bf16_t* knope = (bf16_t*)alloc(MT * 1024 * 2);
    bf16_t* vT    = (bf16_t*)alloc(MT * 2048 * 2);  // [b][h*128+d][t]
    float2* cs    = (float2*)alloc((size_t)2048 * 64 * 8);
    bf16_t* qbuf  = (bf16_t*)d_out;  // d_out scratch until final GEMM
    bf16_t* kbuf  = (bf16_t*)d_out + MT * 2048;
    bf16_t* obuf  = xb;              // xb dead after fused x-GEMM

    k_convert<<<dim3(16384), dim3(256), 0, stream>>>(x, xb, 16777216);
    k_rope_tables<<<dim3(512), 256, 0, stream>>>(cs);
    // packed weight transposes: rows [0,1024)=w_q_down, [1024,1536)=w_kv_down,
    // [1536,1600)=w_k_rope, [1600,3648)=w_gate
    k_transpose<<<dim3(32, 64), 256, 0, stream>>>(w_q_down, Wt, 2048, 1024);
    k_transpose<<<dim3(16, 64), 256, 0, stream>>>(w_kv_down, Wt + (size_t)1024 * 2048, 2048, 512);
    k_transpose<<<dim3(2, 64), 256, 0, stream>>>(w_k_rope, Wt + (size_t)1536 * 2048, 2048, 64);
    k_transpose<<<dim3(64, 64), 256, 0, stream>>>(w_gate, Wt + (size_t)1600 * 2048, 2048, 2048);
    k_transpose<<<dim3(64, 32), 256, 0, stream>>>(w_q_up, wqu_t, 1024, 2048);
    k_transpose<<<dim3(32, 16), 256, 0, stream>>>(w_k_up, wku_t, 512, 1024);
    k_transpose<<<dim3(64, 16), 256, 0, stream>>>(w_v_up, wvu_t, 512, 2048);
    k_transpose<<<dim3(64, 64), 256, 0, stream>>>(w_o, wo_t, 2048, 2048);
    // fused x-GEMM: ob[M][3648] = xb @ Wt^T
    k_gemm<0><<<dim3(29, 64), 256, 0, stream>>>(xb, 2048, Wt, 2048, ob, OBLD, 8192, 3648, 2048,
                                                0, 0, 0);
    // rmsnorms on qc + ckv column ranges
    k_rmsnorm2<<<dim3(8192), 256, 0, stream>>>(ob, g_q_down, g_kv_down);
    // q_up with fused rope+rmsnorm -> qbuf
    k_gemm_qup<<<dim3(16, 64), 256, 0, stream>>>(ob, OBLD, wqu_t, qbuf, g_q, cs, 1024);
    // k_up
    k_gemm<0><<<dim3(8, 64), 256, 0, stream>>>(ob + 1024, OBLD, wku_t, 512, knope, 1024,
                                               8192, 1024, 512, 0, 0, 0);
    // V^T per batch: vT_b[hd][t] = wvu_t[hd][k] · ckv_b[t][k]
    k_gemm<0><<<dim3(16, 16, 4), 256, 0, stream>>>(wvu_t, 512, ob + 1024, OBLD, vT, 2048,
                                                   2048, 2048, 512, 0, (size_t)2048 * OBLD,
                                                   (size_t)2048 * 2048);
    // assemble k
    k_build_k<<<dim3(32768), 256, 0, stream>>>(knope, ob + 1536, kbuf, g_k, cs);
    // attention + silu(gate)
    k_attn<<<dim3(16, 64), 256, 0, stream>>>(qbuf, kbuf, vT, ob, obuf);
    // output projection
    k_gemm<1><<<dim3(16, 64), 256, 0, stream>>>(obuf, 2048, wo_t, 2048, out, 2048,
                                                8192, 2048, 2048, 0, 0, 0);
}